// Round 4
// baseline (129.000 us; speedup 1.0000x reference)
//
#include <hip/hip_runtime.h>

// Simplex projection along last dim (n = 12288), rows = 4096, fp32.
// wp = max(x - tau, 0), wc = x - wp, tau solves sum(max(x-tau,0)) = Z.
//
// Michelot fixed-point: tau_{k+1} = (sum_{x>tau_k} x - Z)/|{x>tau_k}|, valid
// from any start set containing the support. Bootstrap: threshold stats
// (S_t, C_t) for t in {2,3} accumulated while the row loads; largest t with
// g(t)=S_t-t*C_t >= Z satisfies t <= tau*, actives (~17 for N(0,1)) are
// compacted to LDS and solved redundantly by every wave (no broadcast barrier).
//
// Software pipeline: each block owns 4 rows, two register buffers (A,B);
// the next row's loads are always in flight during the current row's
// solve+store, so the memory system never idles on a block's serial phase.

constexpr int   N_COLS = 12288;
constexpr int   BLOCK  = 512;
constexpr int   NWAVE  = BLOCK / 64;             // 8
constexpr int   V4_PER = N_COLS / (BLOCK * 4);   // 6 float4 per thread
constexpr float Z_LVL  = 1.0f;
constexpr int   CAP    = 1024;                   // LDS compaction capacity
constexpr int   NTHR   = 2;                      // thresholds {2, 3}
constexpr float THR0   = 2.0f;
constexpr int   RPB    = 4;                      // rows per block

typedef float f32x4 __attribute__((ext_vector_type(4)));

struct SharedMem {
  float f[2][NWAVE][NTHR + 1];   // [p][w][0]=full sum, [1+q]=S_q
  int   cnt[2][NWAVE][NTHR];     // [p][w][q]=C_q
  float act[2][CAP];
  float sum2[2][NWAVE];          // iteration-parity buffers (fallback/multiwave)
  int   cnt2[2][NWAVE];
  int   wtot[NWAVE];
};

__device__ __forceinline__ float wave_sum_f(float v) {
#pragma unroll
  for (int off = 32; off >= 1; off >>= 1) v += __shfl_down(v, off, 64);
  return v;
}
__device__ __forceinline__ int wave_sum_i(int v) {
#pragma unroll
  for (int off = 32; off >= 1; off >>= 1) v += __shfl_down(v, off, 64);
  return v;
}
__device__ __forceinline__ float wave_bcast_sum_f(float v) {
#pragma unroll
  for (int off = 32; off >= 1; off >>= 1) v += __shfl_xor(v, off, 64);
  return v;
}

__device__ __forceinline__ void issue_row(const float* __restrict__ x, size_t row,
                                          int tid, f32x4 (&t)[V4_PER]) {
  const f32x4* __restrict__ xin =
      reinterpret_cast<const f32x4*>(x + row * (size_t)N_COLS);
#pragma unroll
  for (int k = 0; k < V4_PER; ++k)
    t[k] = __builtin_nontemporal_load(&xin[tid + k * BLOCK]);
}

__device__ __forceinline__ void store_row(const f32x4 (&t)[V4_PER], float tau,
                                          float* __restrict__ wp, float* __restrict__ wc,
                                          size_t row, int tid) {
  const size_t base = row * (size_t)N_COLS;
  f32x4* __restrict__ wpo = reinterpret_cast<f32x4*>(wp + base);
  f32x4* __restrict__ wco = reinterpret_cast<f32x4*>(wc + base);
#pragma unroll
  for (int k = 0; k < V4_PER; ++k) {
    f32x4 a = t[k], pv, cv;
#pragma unroll
    for (int j = 0; j < 4; ++j) {
      pv[j] = fmaxf(a[j] - tau, 0.f);
      cv[j] = a[j] - pv[j];
    }
    __builtin_nontemporal_store(pv, &wpo[tid + k * BLOCK]);
    __builtin_nontemporal_store(cv, &wco[tid + k * BLOCK]);
  }
}

__device__ __forceinline__ float solve_row(const f32x4 (&t)[V4_PER], SharedMem& sh,
                                           int p, int tid, int lane, int wave) {
  // ---- per-thread stats ----
  float sAll = 0.f;
  float sT[NTHR] = {0.f, 0.f};
  int   cT[NTHR] = {0, 0};
#pragma unroll
  for (int k = 0; k < V4_PER; ++k) {
#pragma unroll
    for (int j = 0; j < 4; ++j) {
      float e = t[k][j];
      sAll += e;
#pragma unroll
      for (int q = 0; q < NTHR; ++q) {
        bool a = e > (THR0 + (float)q);
        sT[q] += a ? e : 0.f;
        cT[q] += a ? 1 : 0;
      }
    }
  }
  sAll = wave_sum_f(sAll);
#pragma unroll
  for (int q = 0; q < NTHR; ++q) { sT[q] = wave_sum_f(sT[q]); cT[q] = wave_sum_i(cT[q]); }
  if (lane == 0) {
    sh.f[p][wave][0] = sAll;
#pragma unroll
    for (int q = 0; q < NTHR; ++q) { sh.f[p][wave][1 + q] = sT[q]; sh.cnt[p][wave][q] = cT[q]; }
  }
  __syncthreads();                                   // B1
  float S = 0.f, ST[NTHR] = {0.f, 0.f};
  int CT[NTHR] = {0, 0};
#pragma unroll
  for (int w = 0; w < NWAVE; ++w) {
    S += sh.f[p][w][0];
#pragma unroll
    for (int q = 0; q < NTHR; ++q) { ST[q] += sh.f[p][w][1 + q]; CT[q] += sh.cnt[p][w][q]; }
  }
  int pick = -1;
#pragma unroll
  for (int q = NTHR - 1; q >= 0; --q)
    if (pick < 0 && CT[q] > 0 && CT[q] <= CAP &&
        (ST[q] - (THR0 + (float)q) * (float)CT[q]) >= Z_LVL + 0.01f) pick = q;

  float tau;
  int   prev;
  int   nact = -1;

  if (pick >= 0) {
    // ---- fast path: compact {x > pick-threshold} into LDS ----
    tau  = (ST[pick] - Z_LVL) / (float)CT[pick];
    prev = CT[pick];
    const float tf = THR0 + (float)pick;
    int nt = 0;
#pragma unroll
    for (int k = 0; k < V4_PER; ++k)
#pragma unroll
      for (int j = 0; j < 4; ++j) nt += (t[k][j] > tf) ? 1 : 0;
    int pre = nt;
#pragma unroll
    for (int off = 1; off < 64; off <<= 1) {
      int u = __shfl_up(pre, off, 64);
      if (lane >= off) pre += u;
    }
    int wb = 0;
#pragma unroll
    for (int w = 0; w < NWAVE; ++w) if (w < wave) wb += sh.cnt[p][w][pick];
    int o = wb + (pre - nt);
#pragma unroll
    for (int k = 0; k < V4_PER; ++k)
#pragma unroll
      for (int j = 0; j < 4; ++j)
        if (t[k][j] > tf) sh.act[p][o++] = t[k][j];
    nact = CT[pick];
    __syncthreads();                                 // B2
  } else {
    // ---- fallback: register Michelot from full-set start (correctness path) ----
    tau  = (S - Z_LVL) / (float)N_COLS;
    prev = N_COLS;
    for (int iter = 0; iter < 48; ++iter) {
      const int pp = iter & 1;
      float ps = 0.f; int pc = 0;
#pragma unroll
      for (int k = 0; k < V4_PER; ++k)
#pragma unroll
        for (int j = 0; j < 4; ++j) {
          bool a = t[k][j] > tau;
          ps += a ? t[k][j] : 0.f;
          pc += a ? 1 : 0;
        }
      ps = wave_sum_f(ps);
      pc = wave_sum_i(pc);
      if (lane == 0) { sh.sum2[pp][wave] = ps; sh.cnt2[pp][wave] = pc; }
      __syncthreads();
      float Sv = 0.f; int C = 0;
#pragma unroll
      for (int w = 0; w < NWAVE; ++w) { Sv += sh.sum2[pp][w]; C += sh.cnt2[pp][w]; }
      tau = (Sv - Z_LVL) / (float)C;
      if (C == prev) return tau;                     // stable -> exact (uniform)
      prev = C;
      if (C <= CAP) {
        int nt = 0;
#pragma unroll
        for (int k = 0; k < V4_PER; ++k)
#pragma unroll
          for (int j = 0; j < 4; ++j) nt += (t[k][j] > tau) ? 1 : 0;
        int pre = nt;
#pragma unroll
        for (int off = 1; off < 64; off <<= 1) {
          int u = __shfl_up(pre, off, 64);
          if (lane >= off) pre += u;
        }
        if (lane == 63) sh.wtot[wave] = pre;
        const int my = pre - nt;
        __syncthreads();
        int wb = 0, ntot = 0;
#pragma unroll
        for (int w = 0; w < NWAVE; ++w) { if (w < wave) wb += sh.wtot[w]; ntot += sh.wtot[w]; }
        int o = wb + my;
#pragma unroll
        for (int k = 0; k < V4_PER; ++k)
#pragma unroll
          for (int j = 0; j < 4; ++j)
            if (t[k][j] > tau) sh.act[p][o++] = t[k][j];
        nact = ntot;
        __syncthreads();
        break;
      }
    }
  }

  // ---- solve on compacted actives ----
  if (nact >= 0) {
    if (nact <= 64) {
      // every wave solves redundantly from LDS -> bit-identical tau, no barrier
      const bool valid = lane < nact;
      const float a = valid ? sh.act[p][lane] : 0.f;
      for (int it = 0; it < 64; ++it) {
        bool g = valid && (a > tau);
        int  C = (int)__popcll(__ballot(g));
        float s = wave_bcast_sum_f(g ? a : 0.f);
        tau = (s - Z_LVL) / (float)C;
        if (C == prev) break;
        prev = C;
      }
    } else {
      for (int it2 = 0; it2 < 64; ++it2) {
        const int pp = it2 & 1;
        float ps = 0.f; int pc = 0;
        for (int i = tid; i < nact; i += BLOCK) {
          float a = sh.act[p][i];
          bool g = a > tau;
          ps += g ? a : 0.f;
          pc += g ? 1 : 0;
        }
        ps = wave_sum_f(ps);
        pc = wave_sum_i(pc);
        if (lane == 0) { sh.sum2[pp][wave] = ps; sh.cnt2[pp][wave] = pc; }
        __syncthreads();
        float Sv = 0.f; int C = 0;
#pragma unroll
        for (int w = 0; w < NWAVE; ++w) { Sv += sh.sum2[pp][w]; C += sh.cnt2[pp][w]; }
        tau = (Sv - Z_LVL) / (float)C;
        if (C == prev) break;
        prev = C;
      }
    }
  }
  return tau;
}

__global__ __launch_bounds__(BLOCK, 4) void simplex_proj_pipe(
    const float* __restrict__ x, float* __restrict__ wp, float* __restrict__ wc,
    int rows) {

  __shared__ SharedMem sh;
  const int tid  = threadIdx.x;
  const int lane = tid & 63;
  const int wave = tid >> 6;
  const size_t r0 = (size_t)blockIdx.x * RPB;
  const int    nr = rows - (int)r0;   // >= 1 by grid construction

  f32x4 tA[V4_PER], tB[V4_PER];

  issue_row(x, r0, tid, tA);
  if (nr > 1) issue_row(x, r0 + 1, tid, tB);

  float tau = solve_row(tA, sh, 0, tid, lane, wave);
  store_row(tA, tau, wp, wc, r0, tid);

  if (nr > 2) issue_row(x, r0 + 2, tid, tA);
  if (nr > 1) {
    tau = solve_row(tB, sh, 1, tid, lane, wave);
    store_row(tB, tau, wp, wc, r0 + 1, tid);
  }

  if (nr > 3) issue_row(x, r0 + 3, tid, tB);
  if (nr > 2) {
    tau = solve_row(tA, sh, 0, tid, lane, wave);
    store_row(tA, tau, wp, wc, r0 + 2, tid);
  }

  if (nr > 3) {
    tau = solve_row(tB, sh, 1, tid, lane, wave);
    store_row(tB, tau, wp, wc, r0 + 3, tid);
  }
}

extern "C" void kernel_launch(void* const* d_in, const int* in_sizes, int n_in,
                              void* d_out, int out_size, void* d_ws, size_t ws_size,
                              hipStream_t stream) {
  const float* x = (const float*)d_in[0];
  const int rows = in_sizes[0] / N_COLS;

  float* wp = (float*)d_out;
  float* wc = wp + (size_t)rows * N_COLS;

  const int nblk = (rows + RPB - 1) / RPB;
  simplex_proj_pipe<<<nblk, BLOCK, 0, stream>>>(x, wp, wc, rows);
}

// Round 5
// 115.326 us; speedup vs baseline: 1.1186x; 1.1186x over previous
//
#include <hip/hip_runtime.h>

// Simplex projection along last dim (n = 12288), rows = 4096, fp32.
// wp = max(x - tau, 0), wc = x - wp, tau solves sum(max(x-tau,0)) = Z.
//
// TWO-PASS STRUCTURE:
//   k1: per-row tau via bootstrap-Michelot (reads x, writes tau[rows] to d_ws).
//       Normal loads -> x allocates in the 256MB Infinity Cache (x = 192MB fits).
//   k2: pure elementwise apply (re-reads x, ideally L3-hit; nt-stores wp/wc).
// This removes store pressure from the solve kernel and removes ALL sync from
// the store kernel, so each pass pipelines cleanly instead of phase-locking.
//
// Michelot fixed-point: tau_{k+1} = (sum_{x>tau_k} x - Z)/|{x>tau_k}|, valid
// from any start threshold t <= tau*. Bootstrap stats (S_t, C_t) for
// t in {2,3} are accumulated during the load; the largest t with
// g(t) = S_t - t*C_t >= Z satisfies t <= tau*.

constexpr int   N_COLS = 12288;
constexpr int   BLOCK  = 256;
constexpr int   NWAVE  = BLOCK / 64;             // 4
constexpr int   V4_PER = N_COLS / (BLOCK * 4);   // 12 float4 per thread
constexpr int   PER    = V4_PER * 4;             // 48 scalars per thread
constexpr float Z_LVL  = 1.0f;
constexpr int   CAP    = 1024;                   // LDS compaction capacity
constexpr int   NTHR   = 2;                      // thresholds {2, 3}
constexpr float THR0   = 2.0f;

typedef float f32x4 __attribute__((ext_vector_type(4)));

__device__ __forceinline__ float wave_sum_f(float v) {
#pragma unroll
  for (int off = 32; off >= 1; off >>= 1) v += __shfl_down(v, off, 64);
  return v;
}
__device__ __forceinline__ int wave_sum_i(int v) {
#pragma unroll
  for (int off = 32; off >= 1; off >>= 1) v += __shfl_down(v, off, 64);
  return v;
}
__device__ __forceinline__ float wave_bcast_sum_f(float v) {
#pragma unroll
  for (int off = 32; off >= 1; off >>= 1) v += __shfl_xor(v, off, 64);
  return v;
}

// ---------------- k1: tau solve (no output streams) ----------------
__global__ __launch_bounds__(BLOCK, 4) void tau_kernel(
    const float* __restrict__ x, float* __restrict__ tau_out) {

  const int    tid  = threadIdx.x;
  const int    lane = tid & 63;
  const int    wave = tid >> 6;
  const size_t base = (size_t)blockIdx.x * N_COLS;
  const f32x4* __restrict__ xin = reinterpret_cast<const f32x4*>(x + base);

  __shared__ float s_f[NWAVE][NTHR + 1];
  __shared__ int   s_i[NWAVE][NTHR];
  __shared__ float s_act[CAP];
  __shared__ float s_sum2[2][NWAVE];
  __shared__ int   s_cnt2[2][NWAVE];
  __shared__ int   s_wtot[NWAVE];

  // ---- load row (NORMAL loads: allocate x in L3 for k2) + stats ----
  float v[PER];
  float sAll = 0.f;
  float sT[NTHR] = {0.f, 0.f};
  int   cT[NTHR] = {0, 0};
#pragma unroll
  for (int k = 0; k < V4_PER; ++k) {
    f32x4 t = xin[tid + k * BLOCK];
    v[4*k+0] = t.x; v[4*k+1] = t.y; v[4*k+2] = t.z; v[4*k+3] = t.w;
#pragma unroll
    for (int j = 0; j < 4; ++j) {
      float e = t[j];
      sAll += e;
#pragma unroll
      for (int q = 0; q < NTHR; ++q) {
        bool a = e > (THR0 + (float)q);
        sT[q] += a ? e : 0.f;
        cT[q] += a ? 1 : 0;
      }
    }
  }

  sAll = wave_sum_f(sAll);
#pragma unroll
  for (int q = 0; q < NTHR; ++q) { sT[q] = wave_sum_f(sT[q]); cT[q] = wave_sum_i(cT[q]); }
  if (lane == 0) {
    s_f[wave][0] = sAll;
#pragma unroll
    for (int q = 0; q < NTHR; ++q) { s_f[wave][1 + q] = sT[q]; s_i[wave][q] = cT[q]; }
  }
  __syncthreads();                                   // B1
  float S = 0.f, ST[NTHR] = {0.f, 0.f};
  int   CT[NTHR] = {0, 0};
#pragma unroll
  for (int w = 0; w < NWAVE; ++w) {
    S += s_f[w][0];
#pragma unroll
    for (int q = 0; q < NTHR; ++q) { ST[q] += s_f[w][1 + q]; CT[q] += s_i[w][q]; }
  }

  int pick = -1;
#pragma unroll
  for (int q = NTHR - 1; q >= 0; --q)
    if (pick < 0 && CT[q] > 0 && CT[q] <= CAP &&
        (ST[q] - (THR0 + (float)q) * (float)CT[q]) >= Z_LVL + 0.01f) pick = q;

  float tau;
  int   prev;
  int   nact = -1;

  if (pick >= 0) {
    tau  = (ST[pick] - Z_LVL) / (float)CT[pick];
    prev = CT[pick];
    const float tf = THR0 + (float)pick;
    int nt = 0;
#pragma unroll
    for (int k = 0; k < PER; ++k) nt += (v[k] > tf) ? 1 : 0;
    int pre = nt;
#pragma unroll
    for (int off = 1; off < 64; off <<= 1) {
      int u = __shfl_up(pre, off, 64);
      if (lane >= off) pre += u;
    }
    int wb = 0;
#pragma unroll
    for (int w = 0; w < NWAVE; ++w) if (w < wave) wb += s_i[w][pick];
    int o = wb + (pre - nt);
#pragma unroll
    for (int k = 0; k < PER; ++k) if (v[k] > tf) s_act[o++] = v[k];
    nact = CT[pick];
    __syncthreads();                                 // B2
  } else {
    // fallback: full-set register Michelot (correctness for arbitrary data)
    tau  = (S - Z_LVL) / (float)N_COLS;
    prev = N_COLS;
    for (int iter = 0; iter < 48; ++iter) {
      const int pp = iter & 1;
      float ps = 0.f; int pc = 0;
#pragma unroll
      for (int k = 0; k < PER; ++k) {
        bool a = v[k] > tau;
        ps += a ? v[k] : 0.f;
        pc += a ? 1 : 0;
      }
      ps = wave_sum_f(ps);
      pc = wave_sum_i(pc);
      if (lane == 0) { s_sum2[pp][wave] = ps; s_cnt2[pp][wave] = pc; }
      __syncthreads();
      float Sv = 0.f; int C = 0;
#pragma unroll
      for (int w = 0; w < NWAVE; ++w) { Sv += s_sum2[pp][w]; C += s_cnt2[pp][w]; }
      tau = (Sv - Z_LVL) / (float)C;
      if (C == prev) { nact = -2; break; }           // converged, tau uniform
      prev = C;
      if (C <= CAP) {
        int nt = 0;
#pragma unroll
        for (int k = 0; k < PER; ++k) nt += (v[k] > tau) ? 1 : 0;
        int pre = nt;
#pragma unroll
        for (int off = 1; off < 64; off <<= 1) {
          int u = __shfl_up(pre, off, 64);
          if (lane >= off) pre += u;
        }
        if (lane == 63) s_wtot[wave] = pre;
        const int my = pre - nt;
        __syncthreads();
        int wb = 0, ntot = 0;
#pragma unroll
        for (int w = 0; w < NWAVE; ++w) { if (w < wave) wb += s_wtot[w]; ntot += s_wtot[w]; }
        int o = wb + my;
#pragma unroll
        for (int k = 0; k < PER; ++k) if (v[k] > tau) s_act[o++] = v[k];
        nact = ntot;
        __syncthreads();
        break;
      }
    }
  }

  if (nact >= 0) {
    if (nact <= 64) {
      // only wave 0 solves (no broadcast needed; thread 0 writes tau)
      if (wave == 0) {
        const bool valid = lane < nact;
        const float a = valid ? s_act[lane] : 0.f;
        for (int it = 0; it < 64; ++it) {
          bool g = valid && (a > tau);
          int  C = (int)__popcll(__ballot(g));
          float s = wave_bcast_sum_f(g ? a : 0.f);
          tau = (s - Z_LVL) / (float)C;
          if (C == prev) break;
          prev = C;
        }
      }
    } else {
      for (int it2 = 0; it2 < 64; ++it2) {
        const int pp = it2 & 1;
        float ps = 0.f; int pc = 0;
        for (int i = tid; i < nact; i += BLOCK) {
          float a = s_act[i];
          bool g = a > tau;
          ps += g ? a : 0.f;
          pc += g ? 1 : 0;
        }
        ps = wave_sum_f(ps);
        pc = wave_sum_i(pc);
        if (lane == 0) { s_sum2[pp][wave] = ps; s_cnt2[pp][wave] = pc; }
        __syncthreads();
        float Sv = 0.f; int C = 0;
#pragma unroll
        for (int w = 0; w < NWAVE; ++w) { Sv += s_sum2[pp][w]; C += s_cnt2[pp][w]; }
        tau = (Sv - Z_LVL) / (float)C;
        if (C == prev) break;
        prev = C;
      }
    }
  }

  if (tid == 0) tau_out[blockIdx.x] = tau;
}

// ---------------- k2: elementwise apply (no sync at all) ----------------
__global__ __launch_bounds__(BLOCK, 4) void apply_kernel(
    const float* __restrict__ x, const float* __restrict__ tau_arr,
    float* __restrict__ wp, float* __restrict__ wc) {

  const int    tid = threadIdx.x;
  const int    row = blockIdx.x;
  const float  tau = tau_arr[row];   // uniform -> scalar load
  const size_t base = (size_t)row * N_COLS;
  const f32x4* __restrict__ xin = reinterpret_cast<const f32x4*>(x + base);
  f32x4* __restrict__ wpo = reinterpret_cast<f32x4*>(wp + base);
  f32x4* __restrict__ wco = reinterpret_cast<f32x4*>(wc + base);

#pragma unroll
  for (int k = 0; k < V4_PER; ++k) {
    f32x4 a = xin[tid + k * BLOCK];  // normal load: L3-hit if x resident
    f32x4 pv, cv;
#pragma unroll
    for (int j = 0; j < 4; ++j) {
      pv[j] = fmaxf(a[j] - tau, 0.f);
      cv[j] = a[j] - pv[j];
    }
    __builtin_nontemporal_store(pv, &wpo[tid + k * BLOCK]);
    __builtin_nontemporal_store(cv, &wco[tid + k * BLOCK]);
  }
}

extern "C" void kernel_launch(void* const* d_in, const int* in_sizes, int n_in,
                              void* d_out, int out_size, void* d_ws, size_t ws_size,
                              hipStream_t stream) {
  const float* x = (const float*)d_in[0];
  const int rows = in_sizes[0] / N_COLS;

  float* wp = (float*)d_out;
  float* wc = wp + (size_t)rows * N_COLS;
  float* tau_ws = (float*)d_ws;    // rows * 4 bytes of scratch

  tau_kernel<<<rows, BLOCK, 0, stream>>>(x, tau_ws);
  apply_kernel<<<rows, BLOCK, 0, stream>>>(x, tau_ws, wp, wc);
}